// Round 1
// baseline (524.577 us; speedup 1.0000x reference)
//
#include <hip/hip_runtime.h>
#include <math.h>

#define HH 512
#define WW 512
#define BB 32
#define SPLIT 16

// One soft_skeletonize iteration, fused:
//   min_pool = 3x3 min (OOB = +inf), mp = 3x3 max of min_pool (OOB = -inf)
//   x_new = relu(x - relu(mp - min_pool))
__global__ __launch_bounds__(256) void skel_iter(const float* __restrict__ xin,
                                                 float* __restrict__ xout) {
    __shared__ float sx[36][36];
    __shared__ float sm[34][34];
    const int ox = blockIdx.x * 32, oy = blockIdx.y * 32;
    const float* img = xin + (size_t)blockIdx.z * (HH * WW);
    float* outp = xout + (size_t)blockIdx.z * (HH * WW);
    const int tid = threadIdx.y * 32 + threadIdx.x;

    // load 36x36 tile (halo 2); out-of-image -> +INF (ignored by min)
    for (int i = tid; i < 36 * 36; i += 256) {
        int r = i / 36, c = i % 36;
        int gy = oy - 2 + r, gx = ox - 2 + c;
        float v = INFINITY;
        if (gy >= 0 && gy < HH && gx >= 0 && gx < WW) v = img[gy * WW + gx];
        sx[r][c] = v;
    }
    __syncthreads();

    // 3x3 min-pool over 34x34 (halo 1); out-of-image positions -> -INF (ignored by max)
    for (int i = tid; i < 34 * 34; i += 256) {
        int r = i / 34, c = i % 34;
        int gy = oy - 1 + r, gx = ox - 1 + c;
        float v = -INFINITY;
        if (gy >= 0 && gy < HH && gx >= 0 && gx < WW) {
            float m0 = fminf(fminf(sx[r][c],     sx[r][c + 1]),     sx[r][c + 2]);
            float m1 = fminf(fminf(sx[r + 1][c], sx[r + 1][c + 1]), sx[r + 1][c + 2]);
            float m2 = fminf(fminf(sx[r + 2][c], sx[r + 2][c + 1]), sx[r + 2][c + 2]);
            v = fminf(fminf(m0, m1), m2);
        }
        sm[r][c] = v;
    }
    __syncthreads();

    // 32x32 output: contour = relu(maxpool(min_pool) - min_pool); x = relu(x - contour)
    const int tx = threadIdx.x;
    for (int k = 0; k < 4; ++k) {
        int row = threadIdx.y + k * 8;
        float m0 = fmaxf(fmaxf(sm[row][tx],     sm[row][tx + 1]),     sm[row][tx + 2]);
        float m1 = fmaxf(fmaxf(sm[row + 1][tx], sm[row + 1][tx + 1]), sm[row + 1][tx + 2]);
        float m2 = fmaxf(fmaxf(sm[row + 2][tx], sm[row + 2][tx + 1]), sm[row + 2][tx + 2]);
        float mp = fmaxf(fmaxf(m0, m1), m2);
        float minv = sm[row + 1][tx + 1];
        float contour = fmaxf(mp - minv, 0.0f);
        float xv = sx[row + 2][tx + 2];
        outp[(size_t)(oy + row) * WW + (ox + tx)] = fmaxf(xv - contour, 0.0f);
    }
}

// Stage-1 reduction: per (image b, chunk s) compute 4 partial sums:
//   sum(cl_pred*target), sum(cl_pred), sum(skel_t*pred), sum(skel_t)
__global__ __launch_bounds__(256) void reduce_partial(
    const float* __restrict__ clp, const float* __restrict__ tgt,
    const float* __restrict__ skt, const float* __restrict__ prd,
    float* __restrict__ partials) {
    const int b = blockIdx.x, s = blockIdx.y;
    const int N = HH * WW;
    const int chunk = N / SPLIT;
    const size_t base = (size_t)b * N + (size_t)s * chunk;
    float s0 = 0.f, s1 = 0.f, s2 = 0.f, s3 = 0.f;
    for (int i = threadIdx.x * 4; i < chunk; i += 256 * 4) {
        float4 a = *(const float4*)(clp + base + i);
        float4 t = *(const float4*)(tgt + base + i);
        float4 k = *(const float4*)(skt + base + i);
        float4 p = *(const float4*)(prd + base + i);
        s0 += a.x * t.x + a.y * t.y + a.z * t.z + a.w * t.w;
        s1 += a.x + a.y + a.z + a.w;
        s2 += k.x * p.x + k.y * p.y + k.z * p.z + k.w * p.w;
        s3 += k.x + k.y + k.z + k.w;
    }
    // wave (64-lane) shuffle reduce
    for (int off = 32; off; off >>= 1) {
        s0 += __shfl_down(s0, off);
        s1 += __shfl_down(s1, off);
        s2 += __shfl_down(s2, off);
        s3 += __shfl_down(s3, off);
    }
    __shared__ float wsum[4][4];
    const int lane = threadIdx.x & 63, wave = threadIdx.x >> 6;
    if (lane == 0) {
        wsum[wave][0] = s0; wsum[wave][1] = s1;
        wsum[wave][2] = s2; wsum[wave][3] = s3;
    }
    __syncthreads();
    if (threadIdx.x == 0) {
        float* p = partials + ((size_t)(b * SPLIT + s) * 4);
        p[0] = wsum[0][0] + wsum[1][0] + wsum[2][0] + wsum[3][0];
        p[1] = wsum[0][1] + wsum[1][1] + wsum[2][1] + wsum[3][1];
        p[2] = wsum[0][2] + wsum[1][2] + wsum[2][2] + wsum[3][2];
        p[3] = wsum[0][3] + wsum[1][3] + wsum[2][3] + wsum[3][3];
    }
}

// Stage 2: combine partials, compute iflat/tflat per image, final scalar loss.
__global__ __launch_bounds__(64) void finalize(const float* __restrict__ partials,
                                               float* __restrict__ out) {
    const int b = threadIdx.x;  // 0..63, only b<32 are real images
    float iflat = 0.f, tflat = 0.f;
    if (b < BB) {
        float v0 = 0.f, v1 = 0.f, v2 = 0.f, v3 = 0.f;
        for (int s = 0; s < SPLIT; ++s) {
            const float* p = partials + ((size_t)(b * SPLIT + s) * 4);
            v0 += p[0]; v1 += p[1]; v2 += p[2]; v3 += p[3];
        }
        iflat = (v0 + 1e-6f) / (v1 + 1e-6f);
        tflat = (v2 + 1e-6f) / (v3 + 1e-6f);
    }
    float prod = iflat * tflat;
    float ssum = iflat + tflat;
    for (int off = 32; off; off >>= 1) {
        prod += __shfl_down(prod, off);
        ssum += __shfl_down(ssum, off);
    }
    if (threadIdx.x == 0) out[0] = 1.0f - 2.0f * prod / ssum;
}

extern "C" void kernel_launch(void* const* d_in, const int* in_sizes, int n_in,
                              void* d_out, int out_size, void* d_ws, size_t ws_size,
                              hipStream_t stream) {
    const float* pred = (const float*)d_in[0];
    const float* target = (const float*)d_in[1];
    float* out = (float*)d_out;

    char* ws = (char*)d_ws;
    const size_t IMG = (size_t)BB * HH * WW * sizeof(float);  // 32 MB
    float* buf0 = (float*)(ws);
    float* buf1 = (float*)(ws + IMG);
    float* buf2 = (float*)(ws + 2 * IMG);
    float* partials = (float*)(ws + 3 * IMG);

    dim3 grid(WW / 32, HH / 32, BB), block(32, 8);

    // pred skeleton chain: d_in[0] -> buf0 -> buf1 -> buf0 ... ends in buf1 (10 iters)
    {
        const float* src = pred;
        float* bufs[2] = {buf0, buf1};
        for (int i = 0; i < 10; ++i) {
            float* dst = bufs[i & 1];
            skel_iter<<<grid, block, 0, stream>>>(src, dst);
            src = dst;
        }
    }
    const float* cl_pred = buf1;

    // target skeleton chain: d_in[1] -> buf0 -> buf2 -> buf0 ... ends in buf2
    {
        const float* src = target;
        float* bufs[2] = {buf0, buf2};
        for (int i = 0; i < 10; ++i) {
            float* dst = bufs[i & 1];
            skel_iter<<<grid, block, 0, stream>>>(src, dst);
            src = dst;
        }
    }
    const float* skel_t = buf2;

    reduce_partial<<<dim3(BB, SPLIT), 256, 0, stream>>>(cl_pred, target, skel_t, pred, partials);
    finalize<<<1, 64, 0, stream>>>(partials, out);
}

// Round 2
// 396.627 us; speedup vs baseline: 1.3226x; 1.3226x over previous
//
#include <hip/hip_runtime.h>
#include <math.h>

#define HH 512
#define WW 512
#define BB 32
#define SPLIT 16

// T=2 fused skeleton iterations. 64x64 output tile, halo 4 -> 72x72 region.
#define NRR 72
#define NGG 18          // 72 cols / 4
#define AW  76          // padded LDS row stride (76 % 32 = 12 -> banks rotate)

__device__ __forceinline__ float min3f(float a, float b, float c) {
    return fminf(fminf(a, b), c);
}
__device__ __forceinline__ float max3f(float a, float b, float c) {
    return fmaxf(fmaxf(a, b), c);
}

// rowmin/rowmax of 4 outputs from (L.w | A.xyzw | R.x)
__device__ __forceinline__ float4 rowmin4(float4 L, float4 A, float4 R) {
    float4 m;
    m.x = min3f(L.w, A.x, A.y);
    m.y = min3f(A.x, A.y, A.z);
    m.z = min3f(A.y, A.z, A.w);
    m.w = min3f(A.z, A.w, R.x);
    return m;
}
__device__ __forceinline__ float4 rowmax4(float4 L, float4 A, float4 R) {
    float4 m;
    m.x = max3f(L.w, A.x, A.y);
    m.y = max3f(A.x, A.y, A.z);
    m.z = max3f(A.y, A.z, A.w);
    m.w = max3f(A.z, A.w, R.x);
    return m;
}

// srcA: images 0..31, srcB: images 32..63 (z-32). dst: [64][512][512] layout by z.
__global__ __launch_bounds__(256) void skel2(const float* __restrict__ srcA,
                                             const float* __restrict__ srcB,
                                             float* __restrict__ dst) {
    __shared__ float sx[NRR * AW];
    __shared__ float sm[NRR * AW];
    const int ox = blockIdx.x * 64, oy = blockIdx.y * 64;
    const int z = blockIdx.z;
    const float* img = (z < BB) ? (srcA + (size_t)z * (HH * WW))
                                : (srcB + (size_t)(z - BB) * (HH * WW));
    float* outp = dst + (size_t)z * (HH * WW);
    const int tid = threadIdx.x;
    const bool border = (ox == 0) | (ox == WW - 64) | (oy == 0) | (oy == HH - 64);

    // ---- load region: rows gy = oy-4+r (r in [0,72)), cols gx = ox-4+4g..+3 ----
    if (!border) {
        for (int i = tid; i < NRR * NGG; i += 256) {
            int r = i / NGG, g = i % NGG;
            const float* p = img + (size_t)(oy - 4 + r) * WW + (ox - 4 + 4 * g);
            *(float4*)&sx[r * AW + 4 * g] = *(const float4*)p;
        }
    } else {
        for (int i = tid; i < NRR * NGG; i += 256) {
            int r = i / NGG, g = i % NGG;
            int gy = oy - 4 + r, gx0 = ox - 4 + 4 * g;
            float4 v;
            if (gy >= 0 && gy < HH && gx0 >= 0 && gx0 + 3 < WW) {
                v = *(const float4*)(img + (size_t)gy * WW + gx0);
            } else if (gy >= 0 && gy < HH) {
                const float* row = img + (size_t)gy * WW;
                v.x = ((unsigned)(gx0)     < WW) ? row[gx0]     : INFINITY;
                v.y = ((unsigned)(gx0 + 1) < WW) ? row[gx0 + 1] : INFINITY;
                v.z = ((unsigned)(gx0 + 2) < WW) ? row[gx0 + 2] : INFINITY;
                v.w = ((unsigned)(gx0 + 3) < WW) ? row[gx0 + 3] : INFINITY;
            } else {
                v.x = v.y = v.z = v.w = INFINITY;
            }
            *(float4*)&sx[r * AW + 4 * g] = v;
        }
    }
    __syncthreads();

    #pragma unroll
    for (int t = 0; t < 2; ++t) {
        // ---- M phase: min-pool, rows [1+2t, 71-2t), all 18 groups ----
        {
            const int r0 = 1 + 2 * t, nr = (71 - 2 * t) - r0;
            for (int i = tid; i < nr * NGG; i += 256) {
                int r = r0 + i / NGG, g = i % NGG, c0 = 4 * g;
                int lc = (c0 == 0) ? 0 : c0 - 4;
                float4 rm0, rm1, rm2;
                {
                    const float* row = &sx[(r - 1) * AW];
                    rm0 = rowmin4(*(const float4*)(row + lc), *(const float4*)(row + c0),
                                  *(const float4*)(row + c0 + 4));
                }
                {
                    const float* row = &sx[r * AW];
                    rm1 = rowmin4(*(const float4*)(row + lc), *(const float4*)(row + c0),
                                  *(const float4*)(row + c0 + 4));
                }
                {
                    const float* row = &sx[(r + 1) * AW];
                    rm2 = rowmin4(*(const float4*)(row + lc), *(const float4*)(row + c0),
                                  *(const float4*)(row + c0 + 4));
                }
                float4 mn;
                mn.x = min3f(rm0.x, rm1.x, rm2.x);
                mn.y = min3f(rm0.y, rm1.y, rm2.y);
                mn.z = min3f(rm0.z, rm1.z, rm2.z);
                mn.w = min3f(rm0.w, rm1.w, rm2.w);
                if (border) {
                    // out-of-image min-pool positions must be -INF (ignored by maxpool)
                    int gy = oy - 4 + r, gx0 = ox - 4 + c0;
                    bool rok = (gy >= 0) && (gy < HH);
                    if (!(rok && gx0 >= 0 && gx0 + 3 < WW)) {
                        mn.x = (rok && (unsigned)(gx0)     < WW) ? mn.x : -INFINITY;
                        mn.y = (rok && (unsigned)(gx0 + 1) < WW) ? mn.y : -INFINITY;
                        mn.z = (rok && (unsigned)(gx0 + 2) < WW) ? mn.z : -INFINITY;
                        mn.w = (rok && (unsigned)(gx0 + 3) < WW) ? mn.w : -INFINITY;
                    }
                }
                *(float4*)&sm[r * AW + c0] = mn;
            }
        }
        __syncthreads();
        // ---- U phase: x = relu(x - relu(maxpool(sm) - sm)), rows [2+2t, 70-2t) ----
        {
            const int r0 = 2 + 2 * t, nr = (70 - 2 * t) - r0;
            for (int i = tid; i < nr * NGG; i += 256) {
                int r = r0 + i / NGG, g = i % NGG, c0 = 4 * g;
                int lc = (c0 == 0) ? 0 : c0 - 4;
                float4 rx0, rx1, rx2, mid;
                {
                    const float* row = &sm[(r - 1) * AW];
                    rx0 = rowmax4(*(const float4*)(row + lc), *(const float4*)(row + c0),
                                  *(const float4*)(row + c0 + 4));
                }
                {
                    const float* row = &sm[r * AW];
                    mid = *(const float4*)(row + c0);
                    rx1 = rowmax4(*(const float4*)(row + lc), mid,
                                  *(const float4*)(row + c0 + 4));
                }
                {
                    const float* row = &sm[(r + 1) * AW];
                    rx2 = rowmax4(*(const float4*)(row + lc), *(const float4*)(row + c0),
                                  *(const float4*)(row + c0 + 4));
                }
                float4 mp;
                mp.x = max3f(rx0.x, rx1.x, rx2.x);
                mp.y = max3f(rx0.y, rx1.y, rx2.y);
                mp.z = max3f(rx0.z, rx1.z, rx2.z);
                mp.w = max3f(rx0.w, rx1.w, rx2.w);
                float4 x = *(const float4*)&sx[r * AW + c0];
                float4 xn;
                xn.x = fmaxf(x.x - fmaxf(mp.x - mid.x, 0.f), 0.f);
                xn.y = fmaxf(x.y - fmaxf(mp.y - mid.y, 0.f), 0.f);
                xn.z = fmaxf(x.z - fmaxf(mp.z - mid.z, 0.f), 0.f);
                xn.w = fmaxf(x.w - fmaxf(mp.w - mid.w, 0.f), 0.f);
                if (border) {
                    // out-of-image x stays +INF so later min-pools ignore it
                    int gy = oy - 4 + r, gx0 = ox - 4 + c0;
                    bool rok = (gy >= 0) && (gy < HH);
                    if (!(rok && gx0 >= 0 && gx0 + 3 < WW)) {
                        if (!(rok && (unsigned)(gx0)     < WW)) xn.x = INFINITY;
                        if (!(rok && (unsigned)(gx0 + 1) < WW)) xn.y = INFINITY;
                        if (!(rok && (unsigned)(gx0 + 2) < WW)) xn.z = INFINITY;
                        if (!(rok && (unsigned)(gx0 + 3) < WW)) xn.w = INFINITY;
                    }
                }
                *(float4*)&sx[r * AW + c0] = xn;
            }
        }
        __syncthreads();
    }

    // ---- store output tile: rows [4,68), cols groups 1..16 (c0 = 4..64) ----
    for (int i = tid; i < 64 * 16; i += 256) {
        int r = 4 + i / 16, g = 1 + i % 16, c0 = 4 * g;
        *(float4*)(outp + (size_t)(oy + r - 4) * WW + (ox + c0 - 4)) =
            *(const float4*)&sx[r * AW + c0];
    }
}

// Stage-1 reduction: per (image b, chunk s): sums of clp*tgt, clp, skt*prd, skt
__global__ __launch_bounds__(256) void reduce_partial(
    const float* __restrict__ clp, const float* __restrict__ tgt,
    const float* __restrict__ skt, const float* __restrict__ prd,
    float* __restrict__ partials) {
    const int b = blockIdx.x, s = blockIdx.y;
    const int N = HH * WW;
    const int chunk = N / SPLIT;
    const size_t base = (size_t)b * N + (size_t)s * chunk;
    float s0 = 0.f, s1 = 0.f, s2 = 0.f, s3 = 0.f;
    for (int i = threadIdx.x * 4; i < chunk; i += 256 * 4) {
        float4 a = *(const float4*)(clp + base + i);
        float4 t = *(const float4*)(tgt + base + i);
        float4 k = *(const float4*)(skt + base + i);
        float4 p = *(const float4*)(prd + base + i);
        s0 += a.x * t.x + a.y * t.y + a.z * t.z + a.w * t.w;
        s1 += a.x + a.y + a.z + a.w;
        s2 += k.x * p.x + k.y * p.y + k.z * p.z + k.w * p.w;
        s3 += k.x + k.y + k.z + k.w;
    }
    for (int off = 32; off; off >>= 1) {
        s0 += __shfl_down(s0, off);
        s1 += __shfl_down(s1, off);
        s2 += __shfl_down(s2, off);
        s3 += __shfl_down(s3, off);
    }
    __shared__ float wsum[4][4];
    const int lane = threadIdx.x & 63, wave = threadIdx.x >> 6;
    if (lane == 0) {
        wsum[wave][0] = s0; wsum[wave][1] = s1;
        wsum[wave][2] = s2; wsum[wave][3] = s3;
    }
    __syncthreads();
    if (threadIdx.x == 0) {
        float* p = partials + ((size_t)(b * SPLIT + s) * 4);
        p[0] = wsum[0][0] + wsum[1][0] + wsum[2][0] + wsum[3][0];
        p[1] = wsum[0][1] + wsum[1][1] + wsum[2][1] + wsum[3][1];
        p[2] = wsum[0][2] + wsum[1][2] + wsum[2][2] + wsum[3][2];
        p[3] = wsum[0][3] + wsum[1][3] + wsum[2][3] + wsum[3][3];
    }
}

__global__ __launch_bounds__(64) void finalize(const float* __restrict__ partials,
                                               float* __restrict__ out) {
    const int b = threadIdx.x;
    float iflat = 0.f, tflat = 0.f;
    if (b < BB) {
        float v0 = 0.f, v1 = 0.f, v2 = 0.f, v3 = 0.f;
        for (int s = 0; s < SPLIT; ++s) {
            const float* p = partials + ((size_t)(b * SPLIT + s) * 4);
            v0 += p[0]; v1 += p[1]; v2 += p[2]; v3 += p[3];
        }
        iflat = (v0 + 1e-6f) / (v1 + 1e-6f);
        tflat = (v2 + 1e-6f) / (v3 + 1e-6f);
    }
    float prod = iflat * tflat;
    float ssum = iflat + tflat;
    for (int off = 32; off; off >>= 1) {
        prod += __shfl_down(prod, off);
        ssum += __shfl_down(ssum, off);
    }
    if (threadIdx.x == 0) out[0] = 1.0f - 2.0f * prod / ssum;
}

extern "C" void kernel_launch(void* const* d_in, const int* in_sizes, int n_in,
                              void* d_out, int out_size, void* d_ws, size_t ws_size,
                              hipStream_t stream) {
    const float* pred = (const float*)d_in[0];
    const float* target = (const float*)d_in[1];
    float* out = (float*)d_out;
    char* ws = (char*)d_ws;
    const size_t N = (size_t)HH * WW;
    const size_t HALF = (size_t)BB * N;                 // 32 imgs of floats
    const size_t IMG32 = HALF * sizeof(float);          // 32 MB
    dim3 block(256);

    if (ws_size >= 4 * IMG32 + (1 << 16)) {
        // z=64 path: both chains per dispatch, ping-pong 64MB buffers A<->B
        float* A = (float*)ws;
        float* B = (float*)(ws + 2 * IMG32);
        float* partials = (float*)(ws + 4 * IMG32);
        dim3 grid(WW / 64, HH / 64, 2 * BB);
        skel2<<<grid, block, 0, stream>>>(pred, target, A);
        skel2<<<grid, block, 0, stream>>>(A, A + HALF, B);
        skel2<<<grid, block, 0, stream>>>(B, B + HALF, A);
        skel2<<<grid, block, 0, stream>>>(A, A + HALF, B);
        skel2<<<grid, block, 0, stream>>>(B, B + HALF, A);
        reduce_partial<<<dim3(BB, SPLIT), 256, 0, stream>>>(A, target, A + HALF, pred, partials);
        finalize<<<1, 64, 0, stream>>>(partials, out);
    } else {
        // fallback: z=32 path with 3x32MB buffers
        float* b0 = (float*)ws;
        float* b1 = (float*)(ws + IMG32);
        float* b2 = (float*)(ws + 2 * IMG32);
        float* partials = (float*)(ws + 3 * IMG32);
        dim3 grid(WW / 64, HH / 64, BB);
        // pred chain (10 iters = 5 dispatches): in->b0->b1->b0->b1->b0
        skel2<<<grid, block, 0, stream>>>(pred, pred, b0);
        skel2<<<grid, block, 0, stream>>>(b0, b0, b1);
        skel2<<<grid, block, 0, stream>>>(b1, b1, b0);
        skel2<<<grid, block, 0, stream>>>(b0, b0, b1);
        skel2<<<grid, block, 0, stream>>>(b1, b1, b0);
        // target chain: in->b1->b2->b1->b2->b1
        skel2<<<grid, block, 0, stream>>>(target, target, b1);
        skel2<<<grid, block, 0, stream>>>(b1, b1, b2);
        skel2<<<grid, block, 0, stream>>>(b2, b2, b1);
        skel2<<<grid, block, 0, stream>>>(b1, b1, b2);
        skel2<<<grid, block, 0, stream>>>(b2, b2, b1);
        reduce_partial<<<dim3(BB, SPLIT), 256, 0, stream>>>(b0, target, b1, pred, partials);
        finalize<<<1, 64, 0, stream>>>(partials, out);
    }
}

// Round 3
// 322.223 us; speedup vs baseline: 1.6280x; 1.2309x over previous
//
#include <hip/hip_runtime.h>
#include <math.h>

#define HH 512
#define WW 512
#define BB 32
#define SPLIT 16
#define CHUNK 16

__device__ __forceinline__ float min3f(float a, float b, float c) {
    return fminf(fminf(a, b), c);
}
__device__ __forceinline__ float max3f(float a, float b, float c) {
    return fmaxf(fmaxf(a, b), c);
}
__device__ __forceinline__ float4 ld4(const float* p, bool ok) {
    float4 v;
    if (ok) v = *(const float4*)p;
    else { v.x = INFINITY; v.y = INFINITY; v.z = INFINITY; v.w = INFINITY; }
    return v;
}

// Two fused soft-skeletonize iterations, register-pipelined, no LDS.
// Each thread owns 4 output columns (span s, cols gx0..gx0+3) and walks
// CHUNK+8 rows with a 4-row pipeline lag.
// Semantics per iteration:
//   mn = 3x3 min of x   (x OOB = +INF; mn forced -INF at OOB positions)
//   contour = relu(3x3 max of mn - mn)
//   x' = relu(x - contour)   (x' forced +INF at OOB for next iteration)
__global__ __launch_bounds__(256) void skel2r(const float* __restrict__ srcA,
                                              const float* __restrict__ srcB,
                                              float* __restrict__ dst) {
    const int s = blockIdx.x * 64 + threadIdx.x;            // span 0..127
    const int y0 = (blockIdx.y * 4 + threadIdx.y) * CHUNK;  // output row start
    const int z = blockIdx.z;
    const float* img = (z < BB) ? (srcA + (size_t)z * (HH * WW))
                                : (srcB + (size_t)(z - BB) * (HH * WW));
    float* outp = dst + (size_t)z * (HH * WW);
    const int gx0 = 4 * s;
    const bool lok = (s > 0), rok = (s < 127);

    // static column-validity masks
    bool ok0[10], ok1[8], ok2[6];
    #pragma unroll
    for (int i = 0; i < 10; ++i) { int c = gx0 - 3 + i; ok0[i] = (unsigned)c < WW; }
    #pragma unroll
    for (int j = 0; j < 8; ++j)  { int c = gx0 - 2 + j; ok1[j] = (unsigned)c < WW; }
    #pragma unroll
    for (int k = 0; k < 6; ++k)  { int c = gx0 - 1 + k; ok2[k] = (unsigned)c < WW; }

    // ring state (all statically indexed -> registers)
    float hm0a[10], hm0b[10], mn0p[10];   // horiz-min iter1 (rows R-2,R-1), min-pool row R-2
    float hx0a[8], hx0b[8];               // horiz-max of mn0 (rows R-3,R-2)
    float x0a[8], x0b[8];                 // x0 rows R-2, R-1 (cols gx0-2..gx0+5)
    float hm1a[6], hm1b[6], mn1p[6];      // iter2 analogs
    float hx1a[4], hx1b[4];
    float x1a[4], x1b[4];                 // x1 rows R-4, R-3 (cols gx0..gx0+3)

    #pragma unroll
    for (int i = 0; i < 10; ++i) { hm0a[i] = INFINITY; hm0b[i] = INFINITY; mn0p[i] = -INFINITY; }
    #pragma unroll
    for (int j = 0; j < 8; ++j)  { hx0a[j] = -INFINITY; hx0b[j] = -INFINITY; x0a[j] = INFINITY; x0b[j] = INFINITY; }
    #pragma unroll
    for (int k = 0; k < 6; ++k)  { hm1a[k] = INFINITY; hm1b[k] = INFINITY; mn1p[k] = -INFINITY; }
    #pragma unroll
    for (int m = 0; m < 4; ++m)  { hx1a[m] = -INFINITY; hx1b[m] = -INFINITY; x1a[m] = INFINITY; x1b[m] = INFINITY; }

    for (int rr = 0; rr < CHUNK + 8; ++rr) {
        const int R = y0 - 4 + rr;
        const bool rowok = (unsigned)R < HH;

        // ---- read x0 row R, cols gx0-4 .. gx0+7 (3 x float4) ----
        float xr[12];
        {
            const float* rp = img + (size_t)R * WW + gx0;
            float4 v0 = ld4(rp - 4, rowok && lok);
            float4 v1 = ld4(rp,     rowok);
            float4 v2 = ld4(rp + 4, rowok && rok);
            xr[0] = v0.x; xr[1] = v0.y; xr[2] = v0.z; xr[3] = v0.w;
            xr[4] = v1.x; xr[5] = v1.y; xr[6] = v1.z; xr[7] = v1.w;
            xr[8] = v2.x; xr[9] = v2.y; xr[10] = v2.z; xr[11] = v2.w;
        }

        // ---- iter1 horizontal min, row R (cols gx0-3..gx0+6) ----
        float hm0c[10];
        #pragma unroll
        for (int i = 0; i < 10; ++i) hm0c[i] = min3f(xr[i], xr[i + 1], xr[i + 2]);

        // ---- iter1 min-pool row R-1 ----
        const bool okR1 = (unsigned)(R - 1) < HH;
        float mn0n[10];
        #pragma unroll
        for (int i = 0; i < 10; ++i) {
            float v = min3f(hm0a[i], hm0b[i], hm0c[i]);
            mn0n[i] = (okR1 && ok0[i]) ? v : -INFINITY;
        }

        // ---- horiz max of mn0 row R-1 (cols gx0-2..gx0+5) ----
        float hx0n[8];
        #pragma unroll
        for (int j = 0; j < 8; ++j) hx0n[j] = max3f(mn0n[j], mn0n[j + 1], mn0n[j + 2]);

        // ---- iter1 update: x1 row R-2 ----
        const bool okR2 = (unsigned)(R - 2) < HH;
        float x1n[8];
        #pragma unroll
        for (int j = 0; j < 8; ++j) {
            float mp = max3f(hx0a[j], hx0b[j], hx0n[j]);
            float ct = fmaxf(mp - mn0p[j + 1], 0.0f);
            float v = fmaxf(x0a[j] - ct, 0.0f);
            x1n[j] = (okR2 && ok1[j]) ? v : INFINITY;
        }

        // ---- iter2 horizontal min, row R-2 (cols gx0-1..gx0+4) ----
        float hm1n[6];
        #pragma unroll
        for (int k = 0; k < 6; ++k) hm1n[k] = min3f(x1n[k], x1n[k + 1], x1n[k + 2]);

        // ---- iter2 min-pool row R-3 ----
        const bool okR3 = (unsigned)(R - 3) < HH;
        float mn1n[6];
        #pragma unroll
        for (int k = 0; k < 6; ++k) {
            float v = min3f(hm1a[k], hm1b[k], hm1n[k]);
            mn1n[k] = (okR3 && ok2[k]) ? v : -INFINITY;
        }

        // ---- horiz max of mn1 row R-3 (cols gx0..gx0+3) ----
        float hx1n[4];
        #pragma unroll
        for (int m = 0; m < 4; ++m) hx1n[m] = max3f(mn1n[m], mn1n[m + 1], mn1n[m + 2]);

        // ---- iter2 update: x2 row R-4, write if in output range ----
        if (rr >= 8) {
            float4 o;
            float* po = (float*)&o;
            #pragma unroll
            for (int m = 0; m < 4; ++m) {
                float mp = max3f(hx1a[m], hx1b[m], hx1n[m]);
                float ct = fmaxf(mp - mn1p[m + 1], 0.0f);
                po[m] = fmaxf(x1a[m] - ct, 0.0f);
            }
            *(float4*)(outp + (size_t)(R - 4) * WW + gx0) = o;
        }

        // ---- ring shifts ----
        #pragma unroll
        for (int i = 0; i < 10; ++i) { hm0a[i] = hm0b[i]; hm0b[i] = hm0c[i]; mn0p[i] = mn0n[i]; }
        #pragma unroll
        for (int j = 0; j < 8; ++j)  { hx0a[j] = hx0b[j]; hx0b[j] = hx0n[j]; x0a[j] = x0b[j]; x0b[j] = xr[j + 2]; }
        #pragma unroll
        for (int k = 0; k < 6; ++k)  { hm1a[k] = hm1b[k]; hm1b[k] = hm1n[k]; mn1p[k] = mn1n[k]; }
        #pragma unroll
        for (int m = 0; m < 4; ++m)  { hx1a[m] = hx1b[m]; hx1b[m] = hx1n[m]; x1a[m] = x1b[m]; x1b[m] = x1n[m + 2]; }
    }
}

// Stage-1 reduction: per (image b, chunk s): sums of clp*tgt, clp, skt*prd, skt
__global__ __launch_bounds__(256) void reduce_partial(
    const float* __restrict__ clp, const float* __restrict__ tgt,
    const float* __restrict__ skt, const float* __restrict__ prd,
    float* __restrict__ partials) {
    const int b = blockIdx.x, s = blockIdx.y;
    const int N = HH * WW;
    const int chunk = N / SPLIT;
    const size_t base = (size_t)b * N + (size_t)s * chunk;
    float s0 = 0.f, s1 = 0.f, s2 = 0.f, s3 = 0.f;
    for (int i = threadIdx.x * 4; i < chunk; i += 256 * 4) {
        float4 a = *(const float4*)(clp + base + i);
        float4 t = *(const float4*)(tgt + base + i);
        float4 k = *(const float4*)(skt + base + i);
        float4 p = *(const float4*)(prd + base + i);
        s0 += a.x * t.x + a.y * t.y + a.z * t.z + a.w * t.w;
        s1 += a.x + a.y + a.z + a.w;
        s2 += k.x * p.x + k.y * p.y + k.z * p.z + k.w * p.w;
        s3 += k.x + k.y + k.z + k.w;
    }
    for (int off = 32; off; off >>= 1) {
        s0 += __shfl_down(s0, off);
        s1 += __shfl_down(s1, off);
        s2 += __shfl_down(s2, off);
        s3 += __shfl_down(s3, off);
    }
    __shared__ float wsum[4][4];
    const int lane = threadIdx.x & 63, wave = threadIdx.x >> 6;
    if (lane == 0) {
        wsum[wave][0] = s0; wsum[wave][1] = s1;
        wsum[wave][2] = s2; wsum[wave][3] = s3;
    }
    __syncthreads();
    if (threadIdx.x == 0) {
        float* p = partials + ((size_t)(b * SPLIT + s) * 4);
        p[0] = wsum[0][0] + wsum[1][0] + wsum[2][0] + wsum[3][0];
        p[1] = wsum[0][1] + wsum[1][1] + wsum[2][1] + wsum[3][1];
        p[2] = wsum[0][2] + wsum[1][2] + wsum[2][2] + wsum[3][2];
        p[3] = wsum[0][3] + wsum[1][3] + wsum[2][3] + wsum[3][3];
    }
}

__global__ __launch_bounds__(64) void finalize(const float* __restrict__ partials,
                                               float* __restrict__ out) {
    const int b = threadIdx.x;
    float iflat = 0.f, tflat = 0.f;
    if (b < BB) {
        float v0 = 0.f, v1 = 0.f, v2 = 0.f, v3 = 0.f;
        for (int s = 0; s < SPLIT; ++s) {
            const float* p = partials + ((size_t)(b * SPLIT + s) * 4);
            v0 += p[0]; v1 += p[1]; v2 += p[2]; v3 += p[3];
        }
        iflat = (v0 + 1e-6f) / (v1 + 1e-6f);
        tflat = (v2 + 1e-6f) / (v3 + 1e-6f);
    }
    float prod = iflat * tflat;
    float ssum = iflat + tflat;
    for (int off = 32; off; off >>= 1) {
        prod += __shfl_down(prod, off);
        ssum += __shfl_down(ssum, off);
    }
    if (threadIdx.x == 0) out[0] = 1.0f - 2.0f * prod / ssum;
}

extern "C" void kernel_launch(void* const* d_in, const int* in_sizes, int n_in,
                              void* d_out, int out_size, void* d_ws, size_t ws_size,
                              hipStream_t stream) {
    const float* pred = (const float*)d_in[0];
    const float* target = (const float*)d_in[1];
    float* out = (float*)d_out;
    char* ws = (char*)d_ws;
    const size_t N = (size_t)HH * WW;
    const size_t HALF = (size_t)BB * N;                 // 32 imgs of floats
    const size_t IMG32 = HALF * sizeof(float);          // 32 MB

    dim3 block(64, 4);

    if (ws_size >= 4 * IMG32 + (1 << 16)) {
        // z=64 path: both chains per dispatch, ping-pong 64MB buffers A<->B
        float* A = (float*)ws;
        float* B = (float*)(ws + 2 * IMG32);
        float* partials = (float*)(ws + 4 * IMG32);
        dim3 grid(2, HH / (CHUNK * 4), 2 * BB);
        skel2r<<<grid, block, 0, stream>>>(pred, target, A);
        skel2r<<<grid, block, 0, stream>>>(A, A + HALF, B);
        skel2r<<<grid, block, 0, stream>>>(B, B + HALF, A);
        skel2r<<<grid, block, 0, stream>>>(A, A + HALF, B);
        skel2r<<<grid, block, 0, stream>>>(B, B + HALF, A);
        reduce_partial<<<dim3(BB, SPLIT), 256, 0, stream>>>(A, target, A + HALF, pred, partials);
        finalize<<<1, 64, 0, stream>>>(partials, out);
    } else {
        // fallback: z=32 path with 3x32MB buffers
        float* b0 = (float*)ws;
        float* b1 = (float*)(ws + IMG32);
        float* b2 = (float*)(ws + 2 * IMG32);
        float* partials = (float*)(ws + 3 * IMG32);
        dim3 grid(2, HH / (CHUNK * 4), BB);
        // pred chain (10 iters = 5 dispatches): in->b0->b1->b0->b1->b0
        skel2r<<<grid, block, 0, stream>>>(pred, pred, b0);
        skel2r<<<grid, block, 0, stream>>>(b0, b0, b1);
        skel2r<<<grid, block, 0, stream>>>(b1, b1, b0);
        skel2r<<<grid, block, 0, stream>>>(b0, b0, b1);
        skel2r<<<grid, block, 0, stream>>>(b1, b1, b0);
        // target chain: in->b1->b2->b1->b2->b1
        skel2r<<<grid, block, 0, stream>>>(target, target, b1);
        skel2r<<<grid, block, 0, stream>>>(b1, b1, b2);
        skel2r<<<grid, block, 0, stream>>>(b2, b2, b1);
        skel2r<<<grid, block, 0, stream>>>(b1, b1, b2);
        skel2r<<<grid, block, 0, stream>>>(b2, b2, b1);
        reduce_partial<<<dim3(BB, SPLIT), 256, 0, stream>>>(b0, target, b1, pred, partials);
        finalize<<<1, 64, 0, stream>>>(partials, out);
    }
}

// Round 4
// 274.681 us; speedup vs baseline: 1.9098x; 1.1731x over previous
//
#include <hip/hip_runtime.h>
#include <math.h>

#define HH 512
#define WW 512
#define BB 32
#define SPLIT 16
#define CHUNK 16

__device__ __forceinline__ float min3f(float a, float b, float c) {
    return fminf(fminf(a, b), c);
}
__device__ __forceinline__ float max3f(float a, float b, float c) {
    return fmaxf(fmaxf(a, b), c);
}
__device__ __forceinline__ float4 ld4(const float* p, bool ok) {
    float4 v;
    if (ok) v = *(const float4*)p;
    else { v.x = INFINITY; v.y = INFINITY; v.z = INFINITY; v.w = INFINITY; }
    return v;
}

// Two fused soft-skeletonize iterations, register-pipelined, no LDS.
// Fully unrolled row walk: ring buffers become SSA values (no v_mov shifts),
// warm-up dead stages get DCE'd.
__global__ __launch_bounds__(256) void skel2r(const float* __restrict__ srcA,
                                              const float* __restrict__ srcB,
                                              float* __restrict__ dst) {
    const int s = blockIdx.x * 64 + threadIdx.x;            // span 0..127
    const int y0 = (blockIdx.y * 4 + threadIdx.y) * CHUNK;  // output row start
    const int z = blockIdx.z;
    const float* img = (z < BB) ? (srcA + (size_t)z * (HH * WW))
                                : (srcB + (size_t)(z - BB) * (HH * WW));
    float* outp = dst + (size_t)z * (HH * WW);
    const int gx0 = 4 * s;
    const bool lok = (s > 0), rok = (s < 127);

    // static column-validity masks
    bool ok0[10], ok1[8], ok2[6];
    #pragma unroll
    for (int i = 0; i < 10; ++i) { int c = gx0 - 3 + i; ok0[i] = (unsigned)c < WW; }
    #pragma unroll
    for (int j = 0; j < 8; ++j)  { int c = gx0 - 2 + j; ok1[j] = (unsigned)c < WW; }
    #pragma unroll
    for (int k = 0; k < 6; ++k)  { int c = gx0 - 1 + k; ok2[k] = (unsigned)c < WW; }

    // ring state (fully unrolled loop -> pure register renaming, no movs)
    float hm0a[10], hm0b[10], mn0p[10];
    float hx0a[8], hx0b[8];
    float x0a[8], x0b[8];
    float hm1a[6], hm1b[6], mn1p[6];
    float hx1a[4], hx1b[4];
    float x1a[4], x1b[4];

    #pragma unroll
    for (int i = 0; i < 10; ++i) { hm0a[i] = INFINITY; hm0b[i] = INFINITY; mn0p[i] = -INFINITY; }
    #pragma unroll
    for (int j = 0; j < 8; ++j)  { hx0a[j] = -INFINITY; hx0b[j] = -INFINITY; x0a[j] = INFINITY; x0b[j] = INFINITY; }
    #pragma unroll
    for (int k = 0; k < 6; ++k)  { hm1a[k] = INFINITY; hm1b[k] = INFINITY; mn1p[k] = -INFINITY; }
    #pragma unroll
    for (int m = 0; m < 4; ++m)  { hx1a[m] = -INFINITY; hx1b[m] = -INFINITY; x1a[m] = INFINITY; x1b[m] = INFINITY; }

    #pragma unroll
    for (int rr = 0; rr < CHUNK + 8; ++rr) {
        const int R = y0 - 4 + rr;
        const bool rowok = (unsigned)R < HH;

        // ---- read x0 row R, cols gx0-4 .. gx0+7 (3 x float4) ----
        float xr[12];
        {
            const float* rp = img + (size_t)R * WW + gx0;
            float4 v0 = ld4(rp - 4, rowok && lok);
            float4 v1 = ld4(rp,     rowok);
            float4 v2 = ld4(rp + 4, rowok && rok);
            xr[0] = v0.x; xr[1] = v0.y; xr[2] = v0.z; xr[3] = v0.w;
            xr[4] = v1.x; xr[5] = v1.y; xr[6] = v1.z; xr[7] = v1.w;
            xr[8] = v2.x; xr[9] = v2.y; xr[10] = v2.z; xr[11] = v2.w;
        }

        // ---- iter1 horizontal min, row R ----
        float hm0c[10];
        #pragma unroll
        for (int i = 0; i < 10; ++i) hm0c[i] = min3f(xr[i], xr[i + 1], xr[i + 2]);

        // ---- iter1 min-pool row R-1 ----
        const bool okR1 = (unsigned)(R - 1) < HH;
        float mn0n[10];
        #pragma unroll
        for (int i = 0; i < 10; ++i) {
            float v = min3f(hm0a[i], hm0b[i], hm0c[i]);
            mn0n[i] = (okR1 && ok0[i]) ? v : -INFINITY;
        }

        // ---- horiz max of mn0 row R-1 ----
        float hx0n[8];
        #pragma unroll
        for (int j = 0; j < 8; ++j) hx0n[j] = max3f(mn0n[j], mn0n[j + 1], mn0n[j + 2]);

        // ---- iter1 update: x1 row R-2 ----
        const bool okR2 = (unsigned)(R - 2) < HH;
        float x1n[8];
        #pragma unroll
        for (int j = 0; j < 8; ++j) {
            float mp = max3f(hx0a[j], hx0b[j], hx0n[j]);
            float ct = fmaxf(mp - mn0p[j + 1], 0.0f);
            float v = fmaxf(x0a[j] - ct, 0.0f);
            x1n[j] = (okR2 && ok1[j]) ? v : INFINITY;
        }

        // ---- iter2 horizontal min, row R-2 ----
        float hm1n[6];
        #pragma unroll
        for (int k = 0; k < 6; ++k) hm1n[k] = min3f(x1n[k], x1n[k + 1], x1n[k + 2]);

        // ---- iter2 min-pool row R-3 ----
        const bool okR3 = (unsigned)(R - 3) < HH;
        float mn1n[6];
        #pragma unroll
        for (int k = 0; k < 6; ++k) {
            float v = min3f(hm1a[k], hm1b[k], hm1n[k]);
            mn1n[k] = (okR3 && ok2[k]) ? v : -INFINITY;
        }

        // ---- horiz max of mn1 row R-3 ----
        float hx1n[4];
        #pragma unroll
        for (int m = 0; m < 4; ++m) hx1n[m] = max3f(mn1n[m], mn1n[m + 1], mn1n[m + 2]);

        // ---- iter2 update: x2 row R-4, write if in output range ----
        if (rr >= 8) {
            float4 o;
            float* po = (float*)&o;
            #pragma unroll
            for (int m = 0; m < 4; ++m) {
                float mp = max3f(hx1a[m], hx1b[m], hx1n[m]);
                float ct = fmaxf(mp - mn1p[m + 1], 0.0f);
                po[m] = fmaxf(x1a[m] - ct, 0.0f);
            }
            *(float4*)(outp + (size_t)(R - 4) * WW + gx0) = o;
        }

        // ---- ring shifts (free after full unroll) ----
        #pragma unroll
        for (int i = 0; i < 10; ++i) { hm0a[i] = hm0b[i]; hm0b[i] = hm0c[i]; mn0p[i] = mn0n[i]; }
        #pragma unroll
        for (int j = 0; j < 8; ++j)  { hx0a[j] = hx0b[j]; hx0b[j] = hx0n[j]; x0a[j] = x0b[j]; x0b[j] = xr[j + 2]; }
        #pragma unroll
        for (int k = 0; k < 6; ++k)  { hm1a[k] = hm1b[k]; hm1b[k] = hm1n[k]; mn1p[k] = mn1n[k]; }
        #pragma unroll
        for (int m = 0; m < 4; ++m)  { hx1a[m] = hx1b[m]; hx1b[m] = hx1n[m]; x1a[m] = x1b[m]; x1b[m] = x1n[m + 2]; }
    }
}

// Stage-1 reduction: per (image b, chunk s): sums of clp*tgt, clp, skt*prd, skt
__global__ __launch_bounds__(256) void reduce_partial(
    const float* __restrict__ clp, const float* __restrict__ tgt,
    const float* __restrict__ skt, const float* __restrict__ prd,
    float* __restrict__ partials) {
    const int b = blockIdx.x, s = blockIdx.y;
    const int N = HH * WW;
    const int chunk = N / SPLIT;
    const size_t base = (size_t)b * N + (size_t)s * chunk;
    float s0 = 0.f, s1 = 0.f, s2 = 0.f, s3 = 0.f;
    for (int i = threadIdx.x * 4; i < chunk; i += 256 * 4) {
        float4 a = *(const float4*)(clp + base + i);
        float4 t = *(const float4*)(tgt + base + i);
        float4 k = *(const float4*)(skt + base + i);
        float4 p = *(const float4*)(prd + base + i);
        s0 += a.x * t.x + a.y * t.y + a.z * t.z + a.w * t.w;
        s1 += a.x + a.y + a.z + a.w;
        s2 += k.x * p.x + k.y * p.y + k.z * p.z + k.w * p.w;
        s3 += k.x + k.y + k.z + k.w;
    }
    for (int off = 32; off; off >>= 1) {
        s0 += __shfl_down(s0, off);
        s1 += __shfl_down(s1, off);
        s2 += __shfl_down(s2, off);
        s3 += __shfl_down(s3, off);
    }
    __shared__ float wsum[4][4];
    const int lane = threadIdx.x & 63, wave = threadIdx.x >> 6;
    if (lane == 0) {
        wsum[wave][0] = s0; wsum[wave][1] = s1;
        wsum[wave][2] = s2; wsum[wave][3] = s3;
    }
    __syncthreads();
    if (threadIdx.x == 0) {
        float* p = partials + ((size_t)(b * SPLIT + s) * 4);
        p[0] = wsum[0][0] + wsum[1][0] + wsum[2][0] + wsum[3][0];
        p[1] = wsum[0][1] + wsum[1][1] + wsum[2][1] + wsum[3][1];
        p[2] = wsum[0][2] + wsum[1][2] + wsum[2][2] + wsum[3][2];
        p[3] = wsum[0][3] + wsum[1][3] + wsum[2][3] + wsum[3][3];
    }
}

__global__ __launch_bounds__(64) void finalize(const float* __restrict__ partials,
                                               float* __restrict__ out) {
    const int b = threadIdx.x;
    float iflat = 0.f, tflat = 0.f;
    if (b < BB) {
        float v0 = 0.f, v1 = 0.f, v2 = 0.f, v3 = 0.f;
        for (int s = 0; s < SPLIT; ++s) {
            const float* p = partials + ((size_t)(b * SPLIT + s) * 4);
            v0 += p[0]; v1 += p[1]; v2 += p[2]; v3 += p[3];
        }
        iflat = (v0 + 1e-6f) / (v1 + 1e-6f);
        tflat = (v2 + 1e-6f) / (v3 + 1e-6f);
    }
    float prod = iflat * tflat;
    float ssum = iflat + tflat;
    for (int off = 32; off; off >>= 1) {
        prod += __shfl_down(prod, off);
        ssum += __shfl_down(ssum, off);
    }
    if (threadIdx.x == 0) out[0] = 1.0f - 2.0f * prod / ssum;
}

extern "C" void kernel_launch(void* const* d_in, const int* in_sizes, int n_in,
                              void* d_out, int out_size, void* d_ws, size_t ws_size,
                              hipStream_t stream) {
    const float* pred = (const float*)d_in[0];
    const float* target = (const float*)d_in[1];
    float* out = (float*)d_out;
    char* ws = (char*)d_ws;
    const size_t N = (size_t)HH * WW;
    const size_t HALF = (size_t)BB * N;                 // 32 imgs of floats
    const size_t IMG32 = HALF * sizeof(float);          // 32 MB

    dim3 block(64, 4);

    if (ws_size >= 4 * IMG32 + (1 << 16)) {
        // z=64 path: both chains per dispatch, ping-pong 64MB buffers A<->B
        float* A = (float*)ws;
        float* B = (float*)(ws + 2 * IMG32);
        float* partials = (float*)(ws + 4 * IMG32);
        dim3 grid(2, HH / (CHUNK * 4), 2 * BB);
        skel2r<<<grid, block, 0, stream>>>(pred, target, A);
        skel2r<<<grid, block, 0, stream>>>(A, A + HALF, B);
        skel2r<<<grid, block, 0, stream>>>(B, B + HALF, A);
        skel2r<<<grid, block, 0, stream>>>(A, A + HALF, B);
        skel2r<<<grid, block, 0, stream>>>(B, B + HALF, A);
        reduce_partial<<<dim3(BB, SPLIT), 256, 0, stream>>>(A, target, A + HALF, pred, partials);
        finalize<<<1, 64, 0, stream>>>(partials, out);
    } else {
        // fallback: z=32 path with 3x32MB buffers
        float* b0 = (float*)ws;
        float* b1 = (float*)(ws + IMG32);
        float* b2 = (float*)(ws + 2 * IMG32);
        float* partials = (float*)(ws + 3 * IMG32);
        dim3 grid(2, HH / (CHUNK * 4), BB);
        skel2r<<<grid, block, 0, stream>>>(pred, pred, b0);
        skel2r<<<grid, block, 0, stream>>>(b0, b0, b1);
        skel2r<<<grid, block, 0, stream>>>(b1, b1, b0);
        skel2r<<<grid, block, 0, stream>>>(b0, b0, b1);
        skel2r<<<grid, block, 0, stream>>>(b1, b1, b0);
        skel2r<<<grid, block, 0, stream>>>(target, target, b1);
        skel2r<<<grid, block, 0, stream>>>(b1, b1, b2);
        skel2r<<<grid, block, 0, stream>>>(b2, b2, b1);
        skel2r<<<grid, block, 0, stream>>>(b1, b1, b2);
        skel2r<<<grid, block, 0, stream>>>(b2, b2, b1);
        reduce_partial<<<dim3(BB, SPLIT), 256, 0, stream>>>(b0, target, b1, pred, partials);
        finalize<<<1, 64, 0, stream>>>(partials, out);
    }
}

// Round 5
// 241.499 us; speedup vs baseline: 2.1722x; 1.1374x over previous
//
#include <hip/hip_runtime.h>
#include <math.h>

#define HH 512
#define WW 512
#define BB 32
#define CHUNK 16

__device__ __forceinline__ float min3f(float a, float b, float c) {
    return fminf(fminf(a, b), c);
}
__device__ __forceinline__ float max3f(float a, float b, float c) {
    return fmaxf(fmaxf(a, b), c);
}
__device__ __forceinline__ float4 ld4(const float* p, bool ok) {
    float4 v;
    if (ok) v = *(const float4*)p;
    else { v.x = INFINITY; v.y = INFINITY; v.z = INFINITY; v.w = INFINITY; }
    return v;
}

__device__ __forceinline__ void loadrow(const float* __restrict__ img, int R, int gx0,
                                        bool lok, bool rok, float* xr) {
    const bool rowok = (unsigned)R < HH;
    const float* rp = img + (size_t)R * WW + gx0;
    float4 v0 = ld4(rp - 4, rowok && lok);
    float4 v1 = ld4(rp,     rowok);
    float4 v2 = ld4(rp + 4, rowok && rok);
    xr[0] = v0.x; xr[1] = v0.y; xr[2] = v0.z; xr[3] = v0.w;
    xr[4] = v1.x; xr[5] = v1.y; xr[6] = v1.z; xr[7] = v1.w;
    xr[8] = v2.x; xr[9] = v2.y; xr[10] = v2.z; xr[11] = v2.w;
}

// Two fused soft-skeletonize iterations, register-pipelined, no LDS,
// fully unrolled row walk with depth-2 load prefetch.
// FUSED=1: final pass — instead of storing x2, accumulate
//   acc0 = sum(x2 * companion), acc1 = sum(x2); write per-block partials.
template <int FUSED>
__global__ __launch_bounds__(256) void skel2r_t(const float* __restrict__ srcA,
                                                const float* __restrict__ srcB,
                                                const float* __restrict__ cmpA,
                                                const float* __restrict__ cmpB,
                                                float* __restrict__ dst,
                                                float* __restrict__ partials) {
    const int s = blockIdx.x * 64 + threadIdx.x;            // span 0..127
    const int y0 = (blockIdx.y * 4 + threadIdx.y) * CHUNK;  // output row start
    const int z = blockIdx.z;
    const float* img = (z < BB) ? (srcA + (size_t)z * (HH * WW))
                                : (srcB + (size_t)(z - BB) * (HH * WW));
    const float* cmp = nullptr;
    if (FUSED) cmp = (z < BB) ? (cmpA + (size_t)z * (HH * WW))
                              : (cmpB + (size_t)(z - BB) * (HH * WW));
    float* outp = FUSED ? nullptr : (dst + (size_t)z * (HH * WW));
    const int gx0 = 4 * s;
    const bool lok = (s > 0), rok = (s < 127);

    // static column-validity masks
    bool ok0[10], ok1[8], ok2[6];
    #pragma unroll
    for (int i = 0; i < 10; ++i) { int c = gx0 - 3 + i; ok0[i] = (unsigned)c < WW; }
    #pragma unroll
    for (int j = 0; j < 8; ++j)  { int c = gx0 - 2 + j; ok1[j] = (unsigned)c < WW; }
    #pragma unroll
    for (int k = 0; k < 6; ++k)  { int c = gx0 - 1 + k; ok2[k] = (unsigned)c < WW; }

    // ring state (fully unrolled loop -> pure register renaming)
    float hm0a[10], hm0b[10], mn0p[10];
    float hx0a[8], hx0b[8];
    float x0a[8], x0b[8];
    float hm1a[6], hm1b[6], mn1p[6];
    float hx1a[4], hx1b[4];
    float x1a[4], x1b[4];

    #pragma unroll
    for (int i = 0; i < 10; ++i) { hm0a[i] = INFINITY; hm0b[i] = INFINITY; mn0p[i] = -INFINITY; }
    #pragma unroll
    for (int j = 0; j < 8; ++j)  { hx0a[j] = -INFINITY; hx0b[j] = -INFINITY; x0a[j] = INFINITY; x0b[j] = INFINITY; }
    #pragma unroll
    for (int k = 0; k < 6; ++k)  { hm1a[k] = INFINITY; hm1b[k] = INFINITY; mn1p[k] = -INFINITY; }
    #pragma unroll
    for (int m = 0; m < 4; ++m)  { hx1a[m] = -INFINITY; hx1b[m] = -INFINITY; x1a[m] = INFINITY; x1b[m] = INFINITY; }

    float acc0 = 0.0f, acc1 = 0.0f;

    // depth-2 prefetch: xA = row rr, xB = row rr+1, xC loaded for rr+2
    float xA[12], xB[12];
    loadrow(img, y0 - 4, gx0, lok, rok, xA);
    loadrow(img, y0 - 3, gx0, lok, rok, xB);

    #pragma unroll
    for (int rr = 0; rr < CHUNK + 8; ++rr) {
        const int R = y0 - 4 + rr;

        float xC[12];
        if (rr < CHUNK + 6) {
            loadrow(img, y0 - 2 + rr, gx0, lok, rok, xC);
        } else {
            #pragma unroll
            for (int i = 0; i < 12; ++i) xC[i] = INFINITY;  // dead, DCE'd
        }

        // ---- iter1 horizontal min, row R ----
        float hm0c[10];
        #pragma unroll
        for (int i = 0; i < 10; ++i) hm0c[i] = min3f(xA[i], xA[i + 1], xA[i + 2]);

        // ---- iter1 min-pool row R-1 ----
        const bool okR1 = (unsigned)(R - 1) < HH;
        float mn0n[10];
        #pragma unroll
        for (int i = 0; i < 10; ++i) {
            float v = min3f(hm0a[i], hm0b[i], hm0c[i]);
            mn0n[i] = (okR1 && ok0[i]) ? v : -INFINITY;
        }

        // ---- horiz max of mn0 row R-1 ----
        float hx0n[8];
        #pragma unroll
        for (int j = 0; j < 8; ++j) hx0n[j] = max3f(mn0n[j], mn0n[j + 1], mn0n[j + 2]);

        // ---- iter1 update: x1 row R-2 ----
        const bool okR2 = (unsigned)(R - 2) < HH;
        float x1n[8];
        #pragma unroll
        for (int j = 0; j < 8; ++j) {
            float mp = max3f(hx0a[j], hx0b[j], hx0n[j]);
            float ct = fmaxf(mp - mn0p[j + 1], 0.0f);
            float v = fmaxf(x0a[j] - ct, 0.0f);
            x1n[j] = (okR2 && ok1[j]) ? v : INFINITY;
        }

        // ---- iter2 horizontal min, row R-2 ----
        float hm1n[6];
        #pragma unroll
        for (int k = 0; k < 6; ++k) hm1n[k] = min3f(x1n[k], x1n[k + 1], x1n[k + 2]);

        // ---- iter2 min-pool row R-3 ----
        const bool okR3 = (unsigned)(R - 3) < HH;
        float mn1n[6];
        #pragma unroll
        for (int k = 0; k < 6; ++k) {
            float v = min3f(hm1a[k], hm1b[k], hm1n[k]);
            mn1n[k] = (okR3 && ok2[k]) ? v : -INFINITY;
        }

        // ---- horiz max of mn1 row R-3 ----
        float hx1n[4];
        #pragma unroll
        for (int m = 0; m < 4; ++m) hx1n[m] = max3f(mn1n[m], mn1n[m + 1], mn1n[m + 2]);

        // ---- iter2 update: x2 row R-4 ----
        if (rr >= 8) {
            float o[4];
            #pragma unroll
            for (int m = 0; m < 4; ++m) {
                float mp = max3f(hx1a[m], hx1b[m], hx1n[m]);
                float ct = fmaxf(mp - mn1p[m + 1], 0.0f);
                o[m] = fmaxf(x1a[m] - ct, 0.0f);
            }
            if (FUSED) {
                float4 c4 = *(const float4*)(cmp + (size_t)(R - 4) * WW + gx0);
                acc0 += o[0] * c4.x + o[1] * c4.y + o[2] * c4.z + o[3] * c4.w;
                acc1 += o[0] + o[1] + o[2] + o[3];
            } else {
                float4 ov;
                ov.x = o[0]; ov.y = o[1]; ov.z = o[2]; ov.w = o[3];
                *(float4*)(outp + (size_t)(R - 4) * WW + gx0) = ov;
            }
        }

        // ---- ring shifts (free after full unroll) ----
        #pragma unroll
        for (int i = 0; i < 10; ++i) { hm0a[i] = hm0b[i]; hm0b[i] = hm0c[i]; mn0p[i] = mn0n[i]; }
        #pragma unroll
        for (int j = 0; j < 8; ++j)  { hx0a[j] = hx0b[j]; hx0b[j] = hx0n[j]; x0a[j] = x0b[j]; x0b[j] = xA[j + 2]; }
        #pragma unroll
        for (int k = 0; k < 6; ++k)  { hm1a[k] = hm1b[k]; hm1b[k] = hm1n[k]; mn1p[k] = mn1n[k]; }
        #pragma unroll
        for (int m = 0; m < 4; ++m)  { hx1a[m] = hx1b[m]; hx1b[m] = hx1n[m]; x1a[m] = x1b[m]; x1b[m] = x1n[m + 2]; }
        #pragma unroll
        for (int i = 0; i < 12; ++i) { xA[i] = xB[i]; xB[i] = xC[i]; }
    }

    if (FUSED) {
        // block reduction: 64-lane shuffle, then 4 waves via LDS
        for (int off = 32; off; off >>= 1) {
            acc0 += __shfl_down(acc0, off);
            acc1 += __shfl_down(acc1, off);
        }
        __shared__ float red[4][2];
        if (threadIdx.x == 0) { red[threadIdx.y][0] = acc0; red[threadIdx.y][1] = acc1; }
        __syncthreads();
        if (threadIdx.x == 0 && threadIdx.y == 0) {
            const int tile = blockIdx.x * gridDim.y + blockIdx.y;  // 0..15
            float* p = partials + ((size_t)z * 16 + tile) * 2;
            p[0] = red[0][0] + red[1][0] + red[2][0] + red[3][0];
            p[1] = red[0][1] + red[1][1] + red[2][1] + red[3][1];
        }
    }
}

// partials layout: [z][16 tiles][2]; z<32: (sum clp*tgt, sum clp); z>=32: (sum skt*prd, sum skt)
__global__ __launch_bounds__(64) void finalize2(const float* __restrict__ partials,
                                                float* __restrict__ out) {
    const int b = threadIdx.x;
    float iflat = 0.f, tflat = 0.f;
    if (b < BB) {
        float v0 = 0.f, v1 = 0.f, v2 = 0.f, v3 = 0.f;
        for (int t = 0; t < 16; ++t) {
            v0 += partials[((size_t)b * 16 + t) * 2 + 0];
            v1 += partials[((size_t)b * 16 + t) * 2 + 1];
            v2 += partials[((size_t)(b + BB) * 16 + t) * 2 + 0];
            v3 += partials[((size_t)(b + BB) * 16 + t) * 2 + 1];
        }
        iflat = (v0 + 1e-6f) / (v1 + 1e-6f);
        tflat = (v2 + 1e-6f) / (v3 + 1e-6f);
    }
    float prod = iflat * tflat;
    float ssum = iflat + tflat;
    for (int off = 32; off; off >>= 1) {
        prod += __shfl_down(prod, off);
        ssum += __shfl_down(ssum, off);
    }
    if (threadIdx.x == 0) out[0] = 1.0f - 2.0f * prod / ssum;
}

extern "C" void kernel_launch(void* const* d_in, const int* in_sizes, int n_in,
                              void* d_out, int out_size, void* d_ws, size_t ws_size,
                              hipStream_t stream) {
    const float* pred = (const float*)d_in[0];
    const float* target = (const float*)d_in[1];
    float* out = (float*)d_out;
    char* ws = (char*)d_ws;
    const size_t N = (size_t)HH * WW;
    const size_t HALF = (size_t)BB * N;                 // 32 imgs of floats
    const size_t IMG32 = HALF * sizeof(float);          // 32 MB

    dim3 block(64, 4);
    const int nby = HH / (CHUNK * 4);                   // 8

    if (ws_size >= 4 * IMG32 + (1 << 16)) {
        // z=64 path: both chains per dispatch, ping-pong 64MB buffers A<->B
        float* A = (float*)ws;
        float* B = (float*)(ws + 2 * IMG32);
        float* partials = (float*)(ws + 4 * IMG32);     // 64*16*2 floats
        dim3 grid(2, nby, 2 * BB);
        skel2r_t<0><<<grid, block, 0, stream>>>(pred, target, nullptr, nullptr, A, nullptr);
        skel2r_t<0><<<grid, block, 0, stream>>>(A, A + HALF, nullptr, nullptr, B, nullptr);
        skel2r_t<0><<<grid, block, 0, stream>>>(B, B + HALF, nullptr, nullptr, A, nullptr);
        skel2r_t<0><<<grid, block, 0, stream>>>(A, A + HALF, nullptr, nullptr, B, nullptr);
        // final pass fused with reduction: z<32 companion=target, z>=32 companion=pred
        skel2r_t<1><<<grid, block, 0, stream>>>(B, B + HALF, target, pred, nullptr, partials);
        finalize2<<<1, 64, 0, stream>>>(partials, out);
    } else {
        // fallback: z=32 path with 2x32MB buffers, fused final pass per chain
        float* b0 = (float*)ws;
        float* b1 = (float*)(ws + IMG32);
        float* partials = (float*)(ws + 2 * IMG32);
        dim3 grid(2, nby, BB);
        // pred chain: pred->b0->b1->b0->b1->sums(z 0..31)
        skel2r_t<0><<<grid, block, 0, stream>>>(pred, pred, nullptr, nullptr, b0, nullptr);
        skel2r_t<0><<<grid, block, 0, stream>>>(b0, b0, nullptr, nullptr, b1, nullptr);
        skel2r_t<0><<<grid, block, 0, stream>>>(b1, b1, nullptr, nullptr, b0, nullptr);
        skel2r_t<0><<<grid, block, 0, stream>>>(b0, b0, nullptr, nullptr, b1, nullptr);
        skel2r_t<1><<<grid, block, 0, stream>>>(b1, b1, target, target, nullptr, partials);
        // target chain: target->b0->b1->b0->b1->sums(z 32..63 region)
        skel2r_t<0><<<grid, block, 0, stream>>>(target, target, nullptr, nullptr, b0, nullptr);
        skel2r_t<0><<<grid, block, 0, stream>>>(b0, b0, nullptr, nullptr, b1, nullptr);
        skel2r_t<0><<<grid, block, 0, stream>>>(b1, b1, nullptr, nullptr, b0, nullptr);
        skel2r_t<0><<<grid, block, 0, stream>>>(b0, b0, nullptr, nullptr, b1, nullptr);
        skel2r_t<1><<<grid, block, 0, stream>>>(b1, b1, pred, pred, nullptr,
                                                partials + (size_t)BB * 16 * 2);
        finalize2<<<1, 64, 0, stream>>>(partials, out);
    }
}

// Round 6
// 219.012 us; speedup vs baseline: 2.3952x; 1.1027x over previous
//
#include <hip/hip_runtime.h>
#include <math.h>

#define HH 512
#define WW 512
#define BB 32
#define CHUNK 16

__device__ __forceinline__ float min3f(float a, float b, float c) {
    return fminf(fminf(a, b), c);
}
__device__ __forceinline__ float max3f(float a, float b, float c) {
    return fmaxf(fmaxf(a, b), c);
}
__device__ __forceinline__ float4 ld4(const float* p, bool ok) {
    float4 v;
    if (ok) v = *(const float4*)p;
    else { v.x = INFINITY; v.y = INFINITY; v.z = INFINITY; v.w = INFINITY; }
    return v;
}

__device__ __forceinline__ void loadrow(const float* __restrict__ img, int R, int gx0,
                                        bool lok, bool rok, float* xr) {
    const bool rowok = (unsigned)R < HH;
    const float* rp = img + (size_t)R * WW + gx0;
    float4 v0 = ld4(rp - 4, rowok && lok);
    float4 v1 = ld4(rp,     rowok);
    float4 v2 = ld4(rp + 4, rowok && rok);
    xr[0] = v0.x; xr[1] = v0.y; xr[2] = v0.z; xr[3] = v0.w;
    xr[4] = v1.x; xr[5] = v1.y; xr[6] = v1.z; xr[7] = v1.w;
    xr[8] = v2.x; xr[9] = v2.y; xr[10] = v2.z; xr[11] = v2.w;
}

// Two fused soft-skeletonize iterations, register-pipelined, no LDS,
// fully unrolled row walk, depth-2 load prefetch.
// Boundary handling: row masks are wave-uniform branches (threadIdx.y is
// wave-uniform -> never taken for interior chunks); column masks are
// edge-lane (s==0 / s==127) cndmask fixups from loop-invariant lane masks.
// FUSED=1: final pass accumulates acc0=sum(x2*companion), acc1=sum(x2).
template <int FUSED>
__global__ __launch_bounds__(256) void skel2r_t(const float* __restrict__ srcA,
                                                const float* __restrict__ srcB,
                                                const float* __restrict__ cmpA,
                                                const float* __restrict__ cmpB,
                                                float* __restrict__ dst,
                                                float* __restrict__ partials) {
    const int s = blockIdx.x * 64 + threadIdx.x;            // span 0..127
    const int y0 = (blockIdx.y * 4 + threadIdx.y) * CHUNK;  // output row start
    const int z = blockIdx.z;
    const float* img = (z < BB) ? (srcA + (size_t)z * (HH * WW))
                                : (srcB + (size_t)(z - BB) * (HH * WW));
    const float* cmp = nullptr;
    if (FUSED) cmp = (z < BB) ? (cmpA + (size_t)z * (HH * WW))
                              : (cmpB + (size_t)(z - BB) * (HH * WW));
    float* outp = FUSED ? nullptr : (dst + (size_t)z * (HH * WW));
    const int gx0 = 4 * s;
    const bool lok = (s > 0), rok = (s < 127);
    const bool isL = (s == 0), isR = (s == 127);

    // ring state (fully unrolled loop -> pure register renaming)
    float hm0a[10], hm0b[10], mn0p[8];
    float hx0a[8], hx0b[8];
    float x0a[8], x0b[8];
    float hm1a[6], hm1b[6], mn1p[4];
    float hx1a[4], hx1b[4];
    float x1a[4], x1b[4];

    #pragma unroll
    for (int i = 0; i < 10; ++i) { hm0a[i] = INFINITY; hm0b[i] = INFINITY; }
    #pragma unroll
    for (int j = 0; j < 8; ++j)  { mn0p[j] = -INFINITY; hx0a[j] = -INFINITY; hx0b[j] = -INFINITY; x0a[j] = INFINITY; x0b[j] = INFINITY; }
    #pragma unroll
    for (int k = 0; k < 6; ++k)  { hm1a[k] = INFINITY; hm1b[k] = INFINITY; }
    #pragma unroll
    for (int m = 0; m < 4; ++m)  { mn1p[m] = -INFINITY; hx1a[m] = -INFINITY; hx1b[m] = -INFINITY; x1a[m] = INFINITY; x1b[m] = INFINITY; }

    float acc0 = 0.0f, acc1 = 0.0f;

    // depth-2 prefetch: xA = row R, xB = row R+1, xC loaded for R+2
    float xA[12], xB[12];
    loadrow(img, y0 - 4, gx0, lok, rok, xA);
    loadrow(img, y0 - 3, gx0, lok, rok, xB);
    float4 cmpNext;
    cmpNext.x = 0.f; cmpNext.y = 0.f; cmpNext.z = 0.f; cmpNext.w = 0.f;

    #pragma unroll
    for (int rr = 0; rr < CHUNK + 8; ++rr) {
        const int R = y0 - 4 + rr;

        float xC[12];
        if (rr < CHUNK + 6) {
            loadrow(img, R + 2, gx0, lok, rok, xC);
        } else {
            #pragma unroll
            for (int i = 0; i < 12; ++i) xC[i] = INFINITY;  // dead, DCE'd
        }

        float4 cmpCur;
        if (FUSED) {
            cmpCur = cmpNext;
            if (rr >= 7 && rr < CHUNK + 7) {
                cmpNext = *(const float4*)(cmp + (size_t)(R - 3) * WW + gx0);
            }
        }

        // ---- iter1 horizontal min, row R ----
        float hm0c[10];
        #pragma unroll
        for (int i = 0; i < 10; ++i) hm0c[i] = min3f(xA[i], xA[i + 1], xA[i + 2]);

        // ---- iter1 min-pool row R-1 ----
        float mn0n[10];
        #pragma unroll
        for (int i = 0; i < 10; ++i) mn0n[i] = min3f(hm0a[i], hm0b[i], hm0c[i]);
        if (!((unsigned)(R - 1) < HH)) {        // wave-uniform, rarely taken
            #pragma unroll
            for (int i = 0; i < 10; ++i) mn0n[i] = -INFINITY;
        }
        if (isL) { mn0n[0] = -INFINITY; mn0n[1] = -INFINITY; mn0n[2] = -INFINITY; }
        if (isR) { mn0n[7] = -INFINITY; mn0n[8] = -INFINITY; mn0n[9] = -INFINITY; }

        // ---- horiz max of mn0 row R-1 ----
        float hx0n[8];
        #pragma unroll
        for (int j = 0; j < 8; ++j) hx0n[j] = max3f(mn0n[j], mn0n[j + 1], mn0n[j + 2]);

        // ---- iter1 update: x1 row R-2 ----
        float x1n[8];
        #pragma unroll
        for (int j = 0; j < 8; ++j) {
            float mp = max3f(hx0a[j], hx0b[j], hx0n[j]);
            float ct = fmaxf(mp - mn0p[j], 0.0f);
            x1n[j] = fmaxf(x0a[j] - ct, 0.0f);
        }
        if (!((unsigned)(R - 2) < HH)) {
            #pragma unroll
            for (int j = 0; j < 8; ++j) x1n[j] = INFINITY;
        }
        if (isL) { x1n[0] = INFINITY; x1n[1] = INFINITY; }
        if (isR) { x1n[6] = INFINITY; x1n[7] = INFINITY; }

        // ---- iter2 horizontal min, row R-2 ----
        float hm1n[6];
        #pragma unroll
        for (int k = 0; k < 6; ++k) hm1n[k] = min3f(x1n[k], x1n[k + 1], x1n[k + 2]);

        // ---- iter2 min-pool row R-3 ----
        float mn1n[6];
        #pragma unroll
        for (int k = 0; k < 6; ++k) mn1n[k] = min3f(hm1a[k], hm1b[k], hm1n[k]);
        if (!((unsigned)(R - 3) < HH)) {
            #pragma unroll
            for (int k = 0; k < 6; ++k) mn1n[k] = -INFINITY;
        }
        if (isL) mn1n[0] = -INFINITY;
        if (isR) mn1n[5] = -INFINITY;

        // ---- horiz max of mn1 row R-3 ----
        float hx1n[4];
        #pragma unroll
        for (int m = 0; m < 4; ++m) hx1n[m] = max3f(mn1n[m], mn1n[m + 1], mn1n[m + 2]);

        // ---- iter2 update: x2 row R-4 ----
        if (rr >= 8) {
            float o[4];
            #pragma unroll
            for (int m = 0; m < 4; ++m) {
                float mp = max3f(hx1a[m], hx1b[m], hx1n[m]);
                float ct = fmaxf(mp - mn1p[m], 0.0f);
                o[m] = fmaxf(x1a[m] - ct, 0.0f);
            }
            if (FUSED) {
                acc0 += o[0] * cmpCur.x + o[1] * cmpCur.y + o[2] * cmpCur.z + o[3] * cmpCur.w;
                acc1 += o[0] + o[1] + o[2] + o[3];
            } else {
                float4 ov;
                ov.x = o[0]; ov.y = o[1]; ov.z = o[2]; ov.w = o[3];
                *(float4*)(outp + (size_t)(R - 4) * WW + gx0) = ov;
            }
        }

        // ---- ring shifts (free after full unroll) ----
        #pragma unroll
        for (int i = 0; i < 10; ++i) { hm0a[i] = hm0b[i]; hm0b[i] = hm0c[i]; }
        #pragma unroll
        for (int j = 0; j < 8; ++j)  { mn0p[j] = mn0n[j + 1]; hx0a[j] = hx0b[j]; hx0b[j] = hx0n[j]; x0a[j] = x0b[j]; x0b[j] = xA[j + 2]; }
        #pragma unroll
        for (int k = 0; k < 6; ++k)  { hm1a[k] = hm1b[k]; hm1b[k] = hm1n[k]; }
        #pragma unroll
        for (int m = 0; m < 4; ++m)  { mn1p[m] = mn1n[m + 1]; hx1a[m] = hx1b[m]; hx1b[m] = hx1n[m]; x1a[m] = x1b[m]; x1b[m] = x1n[m + 2]; }
        #pragma unroll
        for (int i = 0; i < 12; ++i) { xA[i] = xB[i]; xB[i] = xC[i]; }
    }

    if (FUSED) {
        for (int off = 32; off; off >>= 1) {
            acc0 += __shfl_down(acc0, off);
            acc1 += __shfl_down(acc1, off);
        }
        __shared__ float red[4][2];
        if (threadIdx.x == 0) { red[threadIdx.y][0] = acc0; red[threadIdx.y][1] = acc1; }
        __syncthreads();
        if (threadIdx.x == 0 && threadIdx.y == 0) {
            const int tile = blockIdx.x * gridDim.y + blockIdx.y;  // 0..15
            float* p = partials + ((size_t)z * 16 + tile) * 2;
            p[0] = red[0][0] + red[1][0] + red[2][0] + red[3][0];
            p[1] = red[0][1] + red[1][1] + red[2][1] + red[3][1];
        }
    }
}

// partials layout: [z][16 tiles][2]; z<32: (sum clp*tgt, sum clp); z>=32: (sum skt*prd, sum skt)
__global__ __launch_bounds__(64) void finalize2(const float* __restrict__ partials,
                                                float* __restrict__ out) {
    const int b = threadIdx.x;
    float iflat = 0.f, tflat = 0.f;
    if (b < BB) {
        float v0 = 0.f, v1 = 0.f, v2 = 0.f, v3 = 0.f;
        for (int t = 0; t < 16; ++t) {
            v0 += partials[((size_t)b * 16 + t) * 2 + 0];
            v1 += partials[((size_t)b * 16 + t) * 2 + 1];
            v2 += partials[((size_t)(b + BB) * 16 + t) * 2 + 0];
            v3 += partials[((size_t)(b + BB) * 16 + t) * 2 + 1];
        }
        iflat = (v0 + 1e-6f) / (v1 + 1e-6f);
        tflat = (v2 + 1e-6f) / (v3 + 1e-6f);
    }
    float prod = iflat * tflat;
    float ssum = iflat + tflat;
    for (int off = 32; off; off >>= 1) {
        prod += __shfl_down(prod, off);
        ssum += __shfl_down(ssum, off);
    }
    if (threadIdx.x == 0) out[0] = 1.0f - 2.0f * prod / ssum;
}

extern "C" void kernel_launch(void* const* d_in, const int* in_sizes, int n_in,
                              void* d_out, int out_size, void* d_ws, size_t ws_size,
                              hipStream_t stream) {
    const float* pred = (const float*)d_in[0];
    const float* target = (const float*)d_in[1];
    float* out = (float*)d_out;
    char* ws = (char*)d_ws;
    const size_t N = (size_t)HH * WW;
    const size_t HALF = (size_t)BB * N;                 // 32 imgs of floats
    const size_t IMG32 = HALF * sizeof(float);          // 32 MB

    dim3 block(64, 4);
    const int nby = HH / (CHUNK * 4);                   // 8

    if (ws_size >= 4 * IMG32 + (1 << 16)) {
        // z=64 path: both chains per dispatch, ping-pong 64MB buffers A<->B
        float* A = (float*)ws;
        float* B = (float*)(ws + 2 * IMG32);
        float* partials = (float*)(ws + 4 * IMG32);     // 64*16*2 floats
        dim3 grid(2, nby, 2 * BB);
        skel2r_t<0><<<grid, block, 0, stream>>>(pred, target, nullptr, nullptr, A, nullptr);
        skel2r_t<0><<<grid, block, 0, stream>>>(A, A + HALF, nullptr, nullptr, B, nullptr);
        skel2r_t<0><<<grid, block, 0, stream>>>(B, B + HALF, nullptr, nullptr, A, nullptr);
        skel2r_t<0><<<grid, block, 0, stream>>>(A, A + HALF, nullptr, nullptr, B, nullptr);
        // final pass fused with reduction: z<32 companion=target, z>=32 companion=pred
        skel2r_t<1><<<grid, block, 0, stream>>>(B, B + HALF, target, pred, nullptr, partials);
        finalize2<<<1, 64, 0, stream>>>(partials, out);
    } else {
        // fallback: z=32 path with 2x32MB buffers, fused final pass per chain
        float* b0 = (float*)ws;
        float* b1 = (float*)(ws + IMG32);
        float* partials = (float*)(ws + 2 * IMG32);
        dim3 grid(2, nby, BB);
        skel2r_t<0><<<grid, block, 0, stream>>>(pred, pred, nullptr, nullptr, b0, nullptr);
        skel2r_t<0><<<grid, block, 0, stream>>>(b0, b0, nullptr, nullptr, b1, nullptr);
        skel2r_t<0><<<grid, block, 0, stream>>>(b1, b1, nullptr, nullptr, b0, nullptr);
        skel2r_t<0><<<grid, block, 0, stream>>>(b0, b0, nullptr, nullptr, b1, nullptr);
        skel2r_t<1><<<grid, block, 0, stream>>>(b1, b1, target, target, nullptr, partials);
        skel2r_t<0><<<grid, block, 0, stream>>>(target, target, nullptr, nullptr, b0, nullptr);
        skel2r_t<0><<<grid, block, 0, stream>>>(b0, b0, nullptr, nullptr, b1, nullptr);
        skel2r_t<0><<<grid, block, 0, stream>>>(b1, b1, nullptr, nullptr, b0, nullptr);
        skel2r_t<0><<<grid, block, 0, stream>>>(b0, b0, nullptr, nullptr, b1, nullptr);
        skel2r_t<1><<<grid, block, 0, stream>>>(b1, b1, pred, pred, nullptr,
                                                partials + (size_t)BB * 16 * 2);
        finalize2<<<1, 64, 0, stream>>>(partials, out);
    }
}